// Round 22
// baseline (170.917 us; speedup 1.0000x reference)
//
#include <hip/hip_runtime.h>
#include <math.h>

// Problem constants (from reference)
constexpr int NN  = 100000;   // nodes
constexpr int EE  = 1600000;  // edges
constexpr int IND = 128;      // input dim
constexpr int HID = 64;       // hidden dim

constexpr int NBUCK = (NN + 127) / 128;   // 782 buckets of 128 nodes
constexpr int CAP   = 3840;               // padded bucket capacity (mu~3142, sigma~91 -> 7.7 sigma)
constexpr int CHUNK = 4096;               // edges per multisplit block (391 chunks; run length ~5.2
                                          // keeps bucket-tail lines L2-hot — r17's 2048 regressed 3x)
constexpr int NTILE = NN / 16;            // 6250 MFMA row-tiles
constexpr int NCB   = (EE + CHUNK - 1) / CHUNK;   // 391 multisplit chunks
constexpr int ZOFF  = NN << 7;            // byte offset of the md zero row

using bf16x8 = __attribute__((ext_vector_type(8))) short;
using f32x4v = __attribute__((ext_vector_type(4))) float;

// bf16 helpers (round-to-nearest-even)
__device__ __forceinline__ unsigned short f2bf(float f) {
    union { float f; unsigned int u; } v; v.f = f;
    unsigned int r = (v.u + 0x7FFFu + ((v.u >> 16) & 1u)) >> 16;
    return (unsigned short)r;
}
__device__ __forceinline__ float bitsf(unsigned int u) {
    union { unsigned int x; float f; } t; t.x = u; return t.f;
}
// unpack a uint holding two bf16 (lo = bits 0..15, hi = bits 16..31)
__device__ __forceinline__ void unp(unsigned int u, float& lo, float& hi) {
    lo = bitsf(u << 16); hi = bitsf(u & 0xFFFF0000u);
}

// packed accumulate: one uint2 (4 bf16) into float2 a01,a23 via v_pk_add_f32
// (2 packed adds replace 4 scalar v_add_f32; values/order identical)
#define ACCPK(u) do { \
    float2 v01_, v23_; \
    v01_.x = bitsf((u).x << 16); v01_.y = bitsf((u).x & 0xFFFF0000u); \
    v23_.x = bitsf((u).y << 16); v23_.y = bitsf((u).y & 0xFFFF0000u); \
    asm("v_pk_add_f32 %0, %0, %1" : "+v"(a01) : "v"(v01_)); \
    asm("v_pk_add_f32 %0, %0, %1" : "+v"(a23) : "v"(v23_)); } while (0)

// ---------------- init: zero gcur + both md zero rows -----------------------

__global__ __launch_bounds__(256) void k_init(int* __restrict__ gcur, int* __restrict__ zrow1,
                                              int* __restrict__ zrow2) {
    int i = blockIdx.x * 256 + threadIdx.x;
    if (i < NBUCK) gcur[i] = 0;
    if (i < 32) { zrow1[i] = 0; zrow2[i] = 0; }   // 128 B zero rows at md1[NN], md2[NN]
}

// ---------------- bucketized multisplit + weight prep (merged, 1024 thr) ----

__global__ __launch_bounds__(1024) void k_bscatter(const int* __restrict__ row, const int* __restrict__ col,
                                                   int* __restrict__ gcur, int* __restrict__ ebuf,
                                                   const float* __restrict__ wfc, const float* __restrict__ bfc,
                                                   const float* __restrict__ w1, const float* __restrict__ w2,
                                                   unsigned short* __restrict__ wct, float* __restrict__ bvec,
                                                   unsigned short* __restrict__ w2t) {
    __shared__ int lhist[NBUCK];
    __shared__ int lbase[NBUCK];
    __shared__ int lcur[NBUCK];
    __shared__ int lcol[CHUNK];          // 16 KB chunk col buffer
    const int tx = threadIdx.x;

    if (blockIdx.x >= NCB) {             // ---- weight-prep blocks (1024 thr) ----
        int b = blockIdx.x - NCB;
        if (b < 8) {                     // Wc^T: 8192 entries
            int idx = b * 1024 + tx;
            int k = idx >> 6, c = idx & 63;
            float acc = 0.f;
            #pragma unroll 8
            for (int j = 0; j < 64; ++j) acc += wfc[k * HID + j] * w1[j * HID + c];
            wct[c * IND + k] = f2bf(acc);        // Wc^T: [c][k]
        } else if (b < 12) {             // W2^T: 4096 entries
            int idx = (b - 8) * 1024 + tx;
            int k = idx >> 6, c = idx & 63;
            w2t[c * HID + k] = f2bf(w2[k * HID + c]);
        } else if (tx < 64) {
            float acc = 0.f;
            #pragma unroll 8
            for (int j = 0; j < 64; ++j) acc += bfc[j] * w1[j * HID + tx];
            bvec[tx] = acc;
        }
        return;
    }

    const int cbase = blockIdx.x * CHUNK;

    for (int b = tx; b < NBUCK; b += 1024) lhist[b] = 0;
    __syncthreads();

    #pragma unroll
    for (int i = 0; i < CHUNK / 1024; ++i) {
        int e = cbase + tx + i * 1024;
        int c = (e < EE) ? col[e] : -1;
        lcol[tx + i * 1024] = c;
        if (c >= 0) atomicAdd(&lhist[c >> 7], 1);
    }
    __syncthreads();

    for (int b = tx; b < NBUCK; b += 1024) {
        int c = lhist[b];
        if (c) lbase[b] = atomicAdd(&gcur[b], c);
        lcur[b] = 0;
    }
    __syncthreads();

    #pragma unroll
    for (int i = 0; i < CHUNK / 1024; ++i) {
        int e = cbase + tx + i * 1024;
        if (e < EE) {
            int c = lcol[tx + i * 1024];
            int b = c >> 7;
            int rank = atomicAdd(&lcur[b], 1);
            ebuf[b * CAP + lbase[b] + rank] = (row[e] << 7) | (c & 127);
        }
    }
}

// ---------------- in-place per-bucket node sort + self fold + padding -------

__global__ __launch_bounds__(512) void k_bsortip(const int* __restrict__ gcur, int* __restrict__ ebuf,
                                                 int* __restrict__ bc, float* __restrict__ dinv) {
    __shared__ int ebl[CAP];             // 15.4 KB
    __shared__ int h[128];
    __shared__ int sc[128];
    __shared__ int cur[128];
    const int tx = threadIdx.x;
    const int b = blockIdx.x;
    const int cnt = gcur[b];
    int* eb = ebuf + b * CAP;

    if (tx < 128) h[tx] = 0;
    for (int e = tx; e < cnt; e += 512) ebl[e] = eb[e];
    __syncthreads();
    for (int e = tx; e < cnt; e += 512) atomicAdd(&h[ebl[e] & 127], 1);
    __syncthreads();

    int np = 0;
    if (tx < 128) {
        int g = b * 128 + tx;
        int n1 = (g < NN) ? h[tx] + 1 : 0;   // self included; ghosts get nothing
        np = (n1 + 15) & ~15;
        sc[tx] = np;
    }
    __syncthreads();
    #pragma unroll
    for (int o = 1; o < 128; o <<= 1) {
        int add = (tx < 128 && tx >= o) ? sc[tx - o] : 0;
        __syncthreads();
        if (tx < 128) sc[tx] += add;
        __syncthreads();
    }
    if (tx < 128) {
        int g = b * 128 + tx;
        int ex = sc[tx] - np;
        cur[tx] = ex + 1;
        if (g < NN) {
            int n1 = h[tx] + 1;
            bc[g]   = (ex << 16) | np;
            dinv[g] = rsqrtf((float)n1);
            if (ex < CAP) eb[ex] = g << 7;           // self entry
            int end = ex + np; if (end > CAP) end = CAP;
            for (int p = ex + n1; p < end; ++p) eb[p] = ZOFF;   // padding
        }
    }
    __syncthreads();

    for (int e = tx; e < cnt; e += 512) {
        int v = ebl[e];
        int r = atomicAdd(&cur[v & 127], 1);
        if (r < CAP) eb[r] = v & 0xFFFFFF80;         // row byte offset
    }
}

// ---------------- fused fc+conv1 transform via MFMA (round-14 proven) -------

__global__ __launch_bounds__(256) void k_mmx(const float* __restrict__ x,
        const unsigned short* __restrict__ wct, const float* __restrict__ bvec,
        const float* __restrict__ dinv, unsigned short* __restrict__ mdb) {
    const int tx = threadIdx.x;
    const int lane = tx & 63;
    const int wv = tx >> 6;
    const int l15 = lane & 15, g = lane >> 4;
    const int tile = blockIdx.x * 4 + wv;
    if (tile >= NTILE) return;           // no barriers in this kernel
    const int row0 = tile * 16;

    // B fragments: 4 n-tiles x 4 k-chunks (16 KB table, L1/L2-hot)
    bf16x8 bf[4][4];
    #pragma unroll
    for (int t = 0; t < 4; ++t) {
        const unsigned short* bp = wct + (t * 16 + l15) * IND + g * 8;
        #pragma unroll
        for (int kc = 0; kc < 4; ++kc)
            bf[t][kc] = *(const bf16x8*)(bp + kc * 32);
    }

    // A fragments: 8 consecutive f32 of x, converted to bf16 in-register
    const float* ap = x + (row0 + l15) * IND + g * 8;
    bf16x8 af[4];
    #pragma unroll
    for (int kc = 0; kc < 4; ++kc) {
        float4 lo = *(const float4*)(ap + kc * 32);
        float4 hi = *(const float4*)(ap + kc * 32 + 4);
        bf16x8 f;
        f[0] = (short)f2bf(lo.x); f[1] = (short)f2bf(lo.y);
        f[2] = (short)f2bf(lo.z); f[3] = (short)f2bf(lo.w);
        f[4] = (short)f2bf(hi.x); f[5] = (short)f2bf(hi.y);
        f[6] = (short)f2bf(hi.z); f[7] = (short)f2bf(hi.w);
        af[kc] = f;
    }

    // accumulate (bias init: depends only on output col = t*16 + l15)
    f32x4v acc[4];
    #pragma unroll
    for (int t = 0; t < 4; ++t) {
        float bv = bvec[t * 16 + l15];
        acc[t][0] = bv; acc[t][1] = bv; acc[t][2] = bv; acc[t][3] = bv;
    }
    #pragma unroll
    for (int kc = 0; kc < 4; ++kc) {
        #pragma unroll
        for (int t = 0; t < 4; ++t)
            acc[t] = __builtin_amdgcn_mfma_f32_16x16x32_bf16(af[kc], bf[t][kc], acc[t], 0, 0, 0);
    }

    // epilogue: row = row0 + g*4 + r, col = t*16 + l15
    #pragma unroll
    for (int r = 0; r < 4; ++r) {
        int rowg = row0 + g * 4 + r;
        float di = dinv[rowg];
        #pragma unroll
        for (int t = 0; t < 4; ++t)
            mdb[rowg * HID + t * 16 + l15] = f2bf(acc[t][r] * di);
    }
}

// ---------------- FUSED gather conv1 + conv2 transform ----------------------
// Block = 64 nodes, 4 waves. Phase 1: each wave gathers 16 nodes (padded
// mask-free loop, packed-f32 accumulate), writes h1 rows to an 8 KB LDS
// tile, XOR-swizzled (byte ^= (row&7)<<4). Phase 2: each wave runs one
// 16-row MFMA tile of md2 = bf16((h1@W2)*dinv), A-fragments from LDS.

__global__ __launch_bounds__(256) void k_gmm(const unsigned short* __restrict__ mdb,
        const int* __restrict__ ebuf, const int* __restrict__ bc, const float* __restrict__ dinv,
        const float* __restrict__ b1, const unsigned short* __restrict__ w2t,
        unsigned short* __restrict__ md2) {
    __shared__ unsigned short sh[64 * 64];   // 8 KB swizzled h1 tile
    const int tx = threadIdx.x;
    const int lane = tx & 63;
    const int wv = tx >> 6;
    const int q = lane >> 4, f4 = lane & 15;
    const int nbase = blockIdx.x * 64;
    float4 bj = *(const float4*)&b1[f4 * 4];
    const char* mbase = (const char*)mdb + f4 * 8;

    // ---- phase 1: gather 16 nodes per wave ----
    #pragma unroll 1
    for (int t = 0; t < 16; ++t) {
        int i = nbase + wv * 16 + t;     // wave-uniform
        if (i < NN) {
            int vv = bc[i];
            const int* prq = ebuf + (i >> 7) * CAP + (vv >> 16) + q;
            int n = vv & 0xFFFF;
            float2 a01 = make_float2(0.f, 0.f), a23 = make_float2(0.f, 0.f);
            for (int e = 0; e < n; e += 16) {
                int r0 = prq[e];
                int r1 = prq[e + 4];
                int r2 = prq[e + 8];
                int r3 = prq[e + 12];
                uint2 u0 = *(const uint2*)(mbase + r0);
                uint2 u1 = *(const uint2*)(mbase + r1);
                uint2 u2 = *(const uint2*)(mbase + r2);
                uint2 u3 = *(const uint2*)(mbase + r3);
                ACCPK(u0); ACCPK(u1); ACCPK(u2); ACCPK(u3);
            }
            float a0 = a01.x, a1 = a01.y, a2 = a23.x, a3 = a23.y;
            a0 += __shfl_xor(a0, 32, 64); a1 += __shfl_xor(a1, 32, 64);
            a2 += __shfl_xor(a2, 32, 64); a3 += __shfl_xor(a3, 32, 64);
            a0 += __shfl_xor(a0, 16, 64); a1 += __shfl_xor(a1, 16, 64);
            a2 += __shfl_xor(a2, 16, 64); a3 += __shfl_xor(a3, 16, 64);

            if (q == 0) {
                int il = wv * 16 + t;    // local row 0..63
                float di = dinv[i];
                ushort4 o;
                o.x = f2bf(fmaxf(di * a0 + bj.x, 0.f));
                o.y = f2bf(fmaxf(di * a1 + bj.y, 0.f));
                o.z = f2bf(fmaxf(di * a2 + bj.z, 0.f));
                o.w = f2bf(fmaxf(di * a3 + bj.w, 0.f));
                *(ushort4*)((char*)sh + il * 128 + ((f4 * 8) ^ ((il & 7) << 4))) = o;
            }
        }
    }
    __syncthreads();

    // ---- phase 2: MFMA conv2 transform, one 16-row tile per wave ----
    const int row0g = nbase + wv * 16;
    if (row0g >= NN) return;
    const int l15 = lane & 15, g = lane >> 4;

    bf16x8 bfr[4][2];
    #pragma unroll
    for (int t = 0; t < 4; ++t) {
        const unsigned short* bp = w2t + (t * 16 + l15) * HID + g * 8;
        bfr[t][0] = *(const bf16x8*)(bp);
        bfr[t][1] = *(const bf16x8*)(bp + 32);
    }
    const int arow = wv * 16 + l15;
    const char* shb = (const char*)sh + arow * 128;
    bf16x8 af0 = *(const bf16x8*)(shb + ((g * 16)      ^ ((arow & 7) << 4)));
    bf16x8 af1 = *(const bf16x8*)(shb + ((g * 16 + 64) ^ ((arow & 7) << 4)));

    f32x4v acc[4] = {};
    #pragma unroll
    for (int t = 0; t < 4; ++t) {
        acc[t] = __builtin_amdgcn_mfma_f32_16x16x32_bf16(af0, bfr[t][0], acc[t], 0, 0, 0);
        acc[t] = __builtin_amdgcn_mfma_f32_16x16x32_bf16(af1, bfr[t][1], acc[t], 0, 0, 0);
    }
    #pragma unroll
    for (int r = 0; r < 4; ++r) {
        int rowg = row0g + g * 4 + r;
        float di = dinv[rowg];
        #pragma unroll
        for (int t = 0; t < 4; ++t)
            md2[rowg * HID + t * 16 + l15] = f2bf(acc[t][r] * di);
    }
}

// ---------------- gather conv2 fused with scores (packed accumulate) --------

__global__ __launch_bounds__(256) void k_gather2s(const unsigned short* __restrict__ mdb,
        const int* __restrict__ ebuf, const int* __restrict__ bc, const float* __restrict__ dinv,
        const float* __restrict__ b, const float* __restrict__ nw, const float* __restrict__ nb,
        const float* __restrict__ ew, float* __restrict__ out_node,
        float* __restrict__ ssrc, float* __restrict__ sdst) {
    int lane = threadIdx.x & 63;
    int q    = lane >> 4;
    int f4   = lane & 15;
    int wid  = (blockIdx.x * blockDim.x + threadIdx.x) >> 6;
    int nwv  = (gridDim.x * blockDim.x) >> 6;
    float4 bj  = *(const float4*)&b[f4 * 4];
    float4 wn  = *(const float4*)&nw[f4 * 4];
    float4 we1 = *(const float4*)&ew[f4 * 4];
    float4 we2 = *(const float4*)&ew[64 + f4 * 4];
    float nb0 = nb[0];
    const char* mbase = (const char*)mdb + f4 * 8;

    for (int i = wid; i < NN; i += nwv) {
        int vv = bc[i];
        const int* prq = ebuf + (i >> 7) * CAP + (vv >> 16) + q;
        int n = vv & 0xFFFF;
        float2 a01 = make_float2(0.f, 0.f), a23 = make_float2(0.f, 0.f);
        for (int e = 0; e < n; e += 16) {
            int r0 = prq[e];
            int r1 = prq[e + 4];
            int r2 = prq[e + 8];
            int r3 = prq[e + 12];
            uint2 u0 = *(const uint2*)(mbase + r0);
            uint2 u1 = *(const uint2*)(mbase + r1);
            uint2 u2 = *(const uint2*)(mbase + r2);
            uint2 u3 = *(const uint2*)(mbase + r3);
            ACCPK(u0); ACCPK(u1); ACCPK(u2); ACCPK(u3);
        }
        float a0 = a01.x, a1 = a01.y, a2 = a23.x, a3 = a23.y;
        a0 += __shfl_xor(a0, 32, 64); a1 += __shfl_xor(a1, 32, 64);
        a2 += __shfl_xor(a2, 32, 64); a3 += __shfl_xor(a3, 32, 64);
        a0 += __shfl_xor(a0, 16, 64); a1 += __shfl_xor(a1, 16, 64);
        a2 += __shfl_xor(a2, 16, 64); a3 += __shfl_xor(a3, 16, 64);

        float di = dinv[i];
        float v0 = fmaxf(di * a0 + bj.x, 0.f);
        float v1 = fmaxf(di * a1 + bj.y, 0.f);
        float v2 = fmaxf(di * a2 + bj.z, 0.f);
        float v3 = fmaxf(di * a3 + bj.w, 0.f);

        float a  = v0 * wn.x  + v1 * wn.y  + v2 * wn.z  + v3 * wn.w;
        float s1 = v0 * we1.x + v1 * we1.y + v2 * we1.z + v3 * we1.w;
        float s2 = v0 * we2.x + v1 * we2.y + v2 * we2.z + v3 * we2.w;
        #pragma unroll
        for (int off = 8; off; off >>= 1) {
            a  += __shfl_xor(a,  off, 64);
            s1 += __shfl_xor(s1, off, 64);
            s2 += __shfl_xor(s2, off, 64);
        }
        if (lane == 0) {
            out_node[i] = 1.f / (1.f + expf(-(a + nb0)));
            ssrc[i] = s1;
            sdst[i] = s2;
        }
    }
}

// ---------------- edge scores (x4 vectorized) -------------------------------

__global__ __launch_bounds__(256) void k_edge(const int4* __restrict__ row4, const int4* __restrict__ col4,
                                              const float* __restrict__ ssrc, const float* __restrict__ sdst,
                                              const float* __restrict__ eb, float4* __restrict__ out4) {
    constexpr int NQ = EE / 4;
    int i = blockIdx.x * 256 + threadIdx.x;
    if (i >= NQ) return;
    float eb0 = eb[0];
    int4 r = row4[i], c = col4[i];
    float4 o;
    float z;
    z = ssrc[r.x] + sdst[c.x] + eb0; o.x = 1.f / (1.f + expf(-z));
    z = ssrc[r.y] + sdst[c.y] + eb0; o.y = 1.f / (1.f + expf(-z));
    z = ssrc[r.z] + sdst[c.z] + eb0; o.z = 1.f / (1.f + expf(-z));
    z = ssrc[r.w] + sdst[c.w] + eb0; o.w = 1.f / (1.f + expf(-z));
    out4[i] = o;
}

extern "C" void kernel_launch(void* const* d_in, const int* in_sizes, int n_in,
                              void* d_out, int out_size, void* d_ws, size_t ws_size,
                              hipStream_t stream) {
    const float* x    = (const float*)d_in[0];
    const int*   ei   = (const int*)d_in[1];
    const float* fc_w = (const float*)d_in[2];
    const float* fc_b = (const float*)d_in[3];
    const float* c1w  = (const float*)d_in[4];
    const float* c1b  = (const float*)d_in[5];
    const float* c2w  = (const float*)d_in[6];
    const float* c2b  = (const float*)d_in[7];
    const float* nw   = (const float*)d_in[8];
    const float* nb   = (const float*)d_in[9];
    const float* ew   = (const float*)d_in[10];
    const float* eb   = (const float*)d_in[11];
    const int* row = ei;        // edge_index[0]
    const int* col = ei + EE;   // edge_index[1]

    // workspace layout (4B units): ~38.5 MB total
    constexpr int NP    = 100352;
    constexpr int MDSZ  = NN * HID / 2 + 32;   // (NN+1) rows of 64 bf16, in floats
    float* ws   = (float*)d_ws;
    float* dinv = ws;                               // NP
    int*   bc   = (int*)(ws + NP);                  // NP
    int*   gcur = (int*)(ws + 2 * NP);              // 1024
    unsigned short* wct = (unsigned short*)(ws + 2 * NP + 1024);  // 8192 bf16 = 4096 f
    float* bvec = ws + 2 * NP + 1024 + 4096;        // 64 (+pad to 128)
    unsigned short* w2t = (unsigned short*)(bvec + 128);          // 4096 bf16 = 2048 f
    int*   ebuf = (int*)(bvec + 128 + 2048);        // NBUCK*CAP
    float* md1f = (float*)(ebuf + NBUCK * CAP);     // md1 bf16 [(NN+1)*HID]
    float* md2f = md1f + MDSZ;                      // md2 bf16 [(NN+1)*HID]
    unsigned short* md1 = (unsigned short*)md1f;
    unsigned short* md2 = (unsigned short*)md2f;
    int* zrow1 = (int*)((char*)md1 + (size_t)NN * HID * 2);
    int* zrow2 = (int*)((char*)md2 + (size_t)NN * HID * 2);
    float* ssrc = md1f;                             // alias: md1 dead after k_gmm
    float* sdst = md1f + NP;

    float* out_edge = (float*)d_out;
    float* out_node = out_edge + EE;

    const int nbQ = (EE / 4 + 255) / 256;       // 1563 edge-quad blocks
    const int nbM = (NTILE + 3) / 4;            // 1563 MFMA blocks (4 waves = 4 tiles)
    const int nbF = (NN + 63) / 64;             // 1563 fused gather+mm blocks

    // ---- init + bucketize (+ weight prep merged) + padded node sort ----
    k_init    <<<(NBUCK + 255) / 256, 256, 0, stream>>>(gcur, zrow1, zrow2);
    k_bscatter<<<NCB + 13, 1024, 0, stream>>>(row, col, gcur, ebuf,
                                              fc_w, fc_b, c1w, c2w, wct, bvec, w2t);
    k_bsortip <<<NBUCK, 512, 0, stream>>>(gcur, ebuf, bc, dinv);

    // ---- MFMA transform 1, fused gather1+conv2 transform ----
    k_mmx<<<nbM, 256, 0, stream>>>(x, wct, bvec, dinv, md1);
    k_gmm<<<nbF, 256, 0, stream>>>(md1, ebuf, bc, dinv, c1b, w2t, md2);

    // ---- gather 2 fused with scores ----
    k_gather2s<<<2048, 256, 0, stream>>>(md2, ebuf, bc, dinv, c2b,
                                         nw, nb, ew, out_node, ssrc, sdst);

    // ---- edge scores ----
    k_edge<<<nbQ, 256, 0, stream>>>((const int4*)row, (const int4*)col,
                                    ssrc, sdst, eb, (float4*)out_edge);
}

// Round 24
// 168.494 us; speedup vs baseline: 1.0144x; 1.0144x over previous
//
#include <hip/hip_runtime.h>
#include <math.h>

// Problem constants (from reference)
constexpr int NN  = 100000;   // nodes
constexpr int EE  = 1600000;  // edges
constexpr int IND = 128;      // input dim
constexpr int HID = 64;       // hidden dim

constexpr int NBUCK = (NN + 127) / 128;   // 782 buckets of 128 nodes
constexpr int CAP   = 3840;               // padded bucket capacity (mu~3142, sigma~91 -> 7.7 sigma)
constexpr int CHUNK = 4096;               // edges per multisplit block (391 chunks; run length ~5.2
                                          // keeps bucket-tail lines L2-hot — r17's 2048 regressed 3x)
constexpr int NTILE = NN / 16;            // 6250 MFMA row-tiles
constexpr int NCB   = (EE + CHUNK - 1) / CHUNK;   // 391 multisplit chunks
constexpr int ZOFF  = NN << 7;            // byte offset of the md zero row

using bf16x8 = __attribute__((ext_vector_type(8))) short;
using f32x4v = __attribute__((ext_vector_type(4))) float;

// bf16 helpers (round-to-nearest-even)
__device__ __forceinline__ unsigned short f2bf(float f) {
    union { float f; unsigned int u; } v; v.f = f;
    unsigned int r = (v.u + 0x7FFFu + ((v.u >> 16) & 1u)) >> 16;
    return (unsigned short)r;
}
// unpack a uint holding two bf16 (lo = bits 0..15, hi = bits 16..31)
__device__ __forceinline__ void unp(unsigned int u, float& lo, float& hi) {
    union { unsigned int x; float f; } a, c;
    a.x = u << 16; c.x = u & 0xFFFF0000u;
    lo = a.f; hi = c.f;
}

// accumulate one uint2 (4 bf16) into a0..a3
#define ACC4(u) do { float l_, h_; \
    unp((u).x, l_, h_); a0 += l_; a1 += h_; \
    unp((u).y, l_, h_); a2 += l_; a3 += h_; } while (0)

// ---------------- init: zero gcur + both md zero rows -----------------------

__global__ __launch_bounds__(256) void k_init(int* __restrict__ gcur, int* __restrict__ zrow1,
                                              int* __restrict__ zrow2) {
    int i = blockIdx.x * 256 + threadIdx.x;
    if (i < NBUCK) gcur[i] = 0;
    if (i < 32) { zrow1[i] = 0; zrow2[i] = 0; }   // 128 B zero rows at md1[NN], md2[NN]
}

// ---------------- bucketized multisplit + weight prep (merged, 1024 thr) ----

__global__ __launch_bounds__(1024) void k_bscatter(const int* __restrict__ row, const int* __restrict__ col,
                                                   int* __restrict__ gcur, int* __restrict__ ebuf,
                                                   const float* __restrict__ wfc, const float* __restrict__ bfc,
                                                   const float* __restrict__ w1, const float* __restrict__ w2,
                                                   unsigned short* __restrict__ wct, float* __restrict__ bvec,
                                                   unsigned short* __restrict__ w2t) {
    __shared__ int lhist[NBUCK];
    __shared__ int lbase[NBUCK];
    __shared__ int lcur[NBUCK];
    __shared__ int lcol[CHUNK];          // 16 KB chunk col buffer
    const int tx = threadIdx.x;

    if (blockIdx.x >= NCB) {             // ---- weight-prep blocks (1024 thr) ----
        int b = blockIdx.x - NCB;
        if (b < 8) {                     // Wc^T: 8192 entries
            int idx = b * 1024 + tx;
            int k = idx >> 6, c = idx & 63;
            float acc = 0.f;
            #pragma unroll 8
            for (int j = 0; j < 64; ++j) acc += wfc[k * HID + j] * w1[j * HID + c];
            wct[c * IND + k] = f2bf(acc);        // Wc^T: [c][k]
        } else if (b < 12) {             // W2^T: 4096 entries
            int idx = (b - 8) * 1024 + tx;
            int k = idx >> 6, c = idx & 63;
            w2t[c * HID + k] = f2bf(w2[k * HID + c]);
        } else if (tx < 64) {
            float acc = 0.f;
            #pragma unroll 8
            for (int j = 0; j < 64; ++j) acc += bfc[j] * w1[j * HID + tx];
            bvec[tx] = acc;
        }
        return;
    }

    const int cbase = blockIdx.x * CHUNK;

    for (int b = tx; b < NBUCK; b += 1024) lhist[b] = 0;
    __syncthreads();

    #pragma unroll
    for (int i = 0; i < CHUNK / 1024; ++i) {
        int e = cbase + tx + i * 1024;
        int c = (e < EE) ? col[e] : -1;
        lcol[tx + i * 1024] = c;
        if (c >= 0) atomicAdd(&lhist[c >> 7], 1);
    }
    __syncthreads();

    for (int b = tx; b < NBUCK; b += 1024) {
        int c = lhist[b];
        if (c) lbase[b] = atomicAdd(&gcur[b], c);
        lcur[b] = 0;
    }
    __syncthreads();

    #pragma unroll
    for (int i = 0; i < CHUNK / 1024; ++i) {
        int e = cbase + tx + i * 1024;
        if (e < EE) {
            int c = lcol[tx + i * 1024];
            int b = c >> 7;
            int rank = atomicAdd(&lcur[b], 1);
            ebuf[b * CAP + lbase[b] + rank] = (row[e] << 7) | (c & 127);
        }
    }
}

// ---------------- in-place per-bucket node sort + self fold + padding -------

__global__ __launch_bounds__(512) void k_bsortip(const int* __restrict__ gcur, int* __restrict__ ebuf,
                                                 int* __restrict__ bc, float* __restrict__ dinv) {
    __shared__ int ebl[CAP];             // 15.4 KB
    __shared__ int h[128];
    __shared__ int sc[128];
    __shared__ int cur[128];
    const int tx = threadIdx.x;
    const int b = blockIdx.x;
    const int cnt = gcur[b];
    int* eb = ebuf + b * CAP;

    if (tx < 128) h[tx] = 0;
    for (int e = tx; e < cnt; e += 512) ebl[e] = eb[e];
    __syncthreads();
    for (int e = tx; e < cnt; e += 512) atomicAdd(&h[ebl[e] & 127], 1);
    __syncthreads();

    int np = 0;
    if (tx < 128) {
        int g = b * 128 + tx;
        int n1 = (g < NN) ? h[tx] + 1 : 0;   // self included; ghosts get nothing
        np = (n1 + 15) & ~15;
        sc[tx] = np;
    }
    __syncthreads();
    #pragma unroll
    for (int o = 1; o < 128; o <<= 1) {
        int add = (tx < 128 && tx >= o) ? sc[tx - o] : 0;
        __syncthreads();
        if (tx < 128) sc[tx] += add;
        __syncthreads();
    }
    if (tx < 128) {
        int g = b * 128 + tx;
        int ex = sc[tx] - np;
        cur[tx] = ex + 1;
        if (g < NN) {
            int n1 = h[tx] + 1;
            bc[g]   = (ex << 16) | np;
            dinv[g] = rsqrtf((float)n1);
            if (ex < CAP) eb[ex] = g << 7;           // self entry
            int end = ex + np; if (end > CAP) end = CAP;
            for (int p = ex + n1; p < end; ++p) eb[p] = ZOFF;   // padding
        }
    }
    __syncthreads();

    for (int e = tx; e < cnt; e += 512) {
        int v = ebl[e];
        int r = atomicAdd(&cur[v & 127], 1);
        if (r < CAP) eb[r] = v & 0xFFFFFF80;         // row byte offset
    }
}

// ---------------- fused fc+conv1 transform via MFMA (round-14 proven) -------

__global__ __launch_bounds__(256) void k_mmx(const float* __restrict__ x,
        const unsigned short* __restrict__ wct, const float* __restrict__ bvec,
        const float* __restrict__ dinv, unsigned short* __restrict__ mdb) {
    const int tx = threadIdx.x;
    const int lane = tx & 63;
    const int wv = tx >> 6;
    const int l15 = lane & 15, g = lane >> 4;
    const int tile = blockIdx.x * 4 + wv;
    if (tile >= NTILE) return;           // no barriers in this kernel
    const int row0 = tile * 16;

    // B fragments: 4 n-tiles x 4 k-chunks (16 KB table, L1/L2-hot)
    bf16x8 bf[4][4];
    #pragma unroll
    for (int t = 0; t < 4; ++t) {
        const unsigned short* bp = wct + (t * 16 + l15) * IND + g * 8;
        #pragma unroll
        for (int kc = 0; kc < 4; ++kc)
            bf[t][kc] = *(const bf16x8*)(bp + kc * 32);
    }

    // A fragments: 8 consecutive f32 of x, converted to bf16 in-register
    const float* ap = x + (row0 + l15) * IND + g * 8;
    bf16x8 af[4];
    #pragma unroll
    for (int kc = 0; kc < 4; ++kc) {
        float4 lo = *(const float4*)(ap + kc * 32);
        float4 hi = *(const float4*)(ap + kc * 32 + 4);
        bf16x8 f;
        f[0] = (short)f2bf(lo.x); f[1] = (short)f2bf(lo.y);
        f[2] = (short)f2bf(lo.z); f[3] = (short)f2bf(lo.w);
        f[4] = (short)f2bf(hi.x); f[5] = (short)f2bf(hi.y);
        f[6] = (short)f2bf(hi.z); f[7] = (short)f2bf(hi.w);
        af[kc] = f;
    }

    // accumulate (bias init: depends only on output col = t*16 + l15)
    f32x4v acc[4];
    #pragma unroll
    for (int t = 0; t < 4; ++t) {
        float bv = bvec[t * 16 + l15];
        acc[t][0] = bv; acc[t][1] = bv; acc[t][2] = bv; acc[t][3] = bv;
    }
    #pragma unroll
    for (int kc = 0; kc < 4; ++kc) {
        #pragma unroll
        for (int t = 0; t < 4; ++t)
            acc[t] = __builtin_amdgcn_mfma_f32_16x16x32_bf16(af[kc], bf[t][kc], acc[t], 0, 0, 0);
    }

    // epilogue: row = row0 + g*4 + r, col = t*16 + l15
    #pragma unroll
    for (int r = 0; r < 4; ++r) {
        int rowg = row0 + g * 4 + r;
        float di = dinv[rowg];
        #pragma unroll
        for (int t = 0; t < 4; ++t)
            mdb[rowg * HID + t * 16 + l15] = f2bf(acc[t][r] * di);
    }
}

// ---------------- FUSED gather conv1 + conv2 transform ----------------------
// Block = 64 nodes, 4 waves. Phase 1: each wave gathers 16 nodes (padded
// mask-free loop), writes h1 rows to an 8 KB LDS tile, XOR-swizzled
// (byte ^= (row&7)<<4 — mask hits bits 4-6 only, so the 8 B ushort4 writes
// and 16 B bf16x8 reads move coherently; writes conflict-free, reads 2-way).
// Phase 2: each wave runs one 16-row MFMA tile of md2 = bf16((h1@W2)*dinv),
// A-fragments from LDS. Kills the h1 HBM round-trip (25.6 MB) + a dispatch.

__global__ __launch_bounds__(256) void k_gmm(const unsigned short* __restrict__ mdb,
        const int* __restrict__ ebuf, const int* __restrict__ bc, const float* __restrict__ dinv,
        const float* __restrict__ b1, const unsigned short* __restrict__ w2t,
        unsigned short* __restrict__ md2) {
    __shared__ unsigned short sh[64 * 64];   // 8 KB swizzled h1 tile
    const int tx = threadIdx.x;
    const int lane = tx & 63;
    const int wv = tx >> 6;
    const int q = lane >> 4, f4 = lane & 15;
    const int nbase = blockIdx.x * 64;
    float4 bj = *(const float4*)&b1[f4 * 4];
    const char* mbase = (const char*)mdb + f4 * 8;

    // ---- phase 1: gather 16 nodes per wave ----
    #pragma unroll 1
    for (int t = 0; t < 16; ++t) {
        int i = nbase + wv * 16 + t;     // wave-uniform
        if (i < NN) {
            int vv = bc[i];
            const int* prq = ebuf + (i >> 7) * CAP + (vv >> 16) + q;
            int n = vv & 0xFFFF;
            float a0 = 0.f, a1 = 0.f, a2 = 0.f, a3 = 0.f;
            for (int e = 0; e < n; e += 16) {
                int r0 = prq[e];
                int r1 = prq[e + 4];
                int r2 = prq[e + 8];
                int r3 = prq[e + 12];
                uint2 u0 = *(const uint2*)(mbase + r0);
                uint2 u1 = *(const uint2*)(mbase + r1);
                uint2 u2 = *(const uint2*)(mbase + r2);
                uint2 u3 = *(const uint2*)(mbase + r3);
                ACC4(u0); ACC4(u1); ACC4(u2); ACC4(u3);
            }
            a0 += __shfl_xor(a0, 32, 64); a1 += __shfl_xor(a1, 32, 64);
            a2 += __shfl_xor(a2, 32, 64); a3 += __shfl_xor(a3, 32, 64);
            a0 += __shfl_xor(a0, 16, 64); a1 += __shfl_xor(a1, 16, 64);
            a2 += __shfl_xor(a2, 16, 64); a3 += __shfl_xor(a3, 16, 64);

            if (q == 0) {
                int il = wv * 16 + t;    // local row 0..63
                float di = dinv[i];
                ushort4 o;
                o.x = f2bf(fmaxf(di * a0 + bj.x, 0.f));
                o.y = f2bf(fmaxf(di * a1 + bj.y, 0.f));
                o.z = f2bf(fmaxf(di * a2 + bj.z, 0.f));
                o.w = f2bf(fmaxf(di * a3 + bj.w, 0.f));
                *(ushort4*)((char*)sh + il * 128 + ((f4 * 8) ^ ((il & 7) << 4))) = o;
            }
        }
    }
    __syncthreads();

    // ---- phase 2: MFMA conv2 transform, one 16-row tile per wave ----
    const int row0g = nbase + wv * 16;
    if (row0g >= NN) return;
    const int l15 = lane & 15, g = lane >> 4;

    bf16x8 bfr[4][2];
    #pragma unroll
    for (int t = 0; t < 4; ++t) {
        const unsigned short* bp = w2t + (t * 16 + l15) * HID + g * 8;
        bfr[t][0] = *(const bf16x8*)(bp);
        bfr[t][1] = *(const bf16x8*)(bp + 32);
    }
    const int arow = wv * 16 + l15;
    const char* shb = (const char*)sh + arow * 128;
    bf16x8 af0 = *(const bf16x8*)(shb + ((g * 16)      ^ ((arow & 7) << 4)));
    bf16x8 af1 = *(const bf16x8*)(shb + ((g * 16 + 64) ^ ((arow & 7) << 4)));

    f32x4v acc[4] = {};
    #pragma unroll
    for (int t = 0; t < 4; ++t) {
        acc[t] = __builtin_amdgcn_mfma_f32_16x16x32_bf16(af0, bfr[t][0], acc[t], 0, 0, 0);
        acc[t] = __builtin_amdgcn_mfma_f32_16x16x32_bf16(af1, bfr[t][1], acc[t], 0, 0, 0);
    }
    #pragma unroll
    for (int r = 0; r < 4; ++r) {
        int rowg = row0g + g * 4 + r;
        float di = dinv[rowg];
        #pragma unroll
        for (int t = 0; t < 4; ++t)
            md2[rowg * HID + t * 16 + l15] = f2bf(acc[t][r] * di);
    }
}

// ---------------- gather conv2 fused with scores ----------------------------

__global__ __launch_bounds__(256) void k_gather2s(const unsigned short* __restrict__ mdb,
        const int* __restrict__ ebuf, const int* __restrict__ bc, const float* __restrict__ dinv,
        const float* __restrict__ b, const float* __restrict__ nw, const float* __restrict__ nb,
        const float* __restrict__ ew, float* __restrict__ out_node,
        float* __restrict__ ssrc, float* __restrict__ sdst) {
    int lane = threadIdx.x & 63;
    int q    = lane >> 4;
    int f4   = lane & 15;
    int wid  = (blockIdx.x * blockDim.x + threadIdx.x) >> 6;
    int nwv  = (gridDim.x * blockDim.x) >> 6;
    float4 bj  = *(const float4*)&b[f4 * 4];
    float4 wn  = *(const float4*)&nw[f4 * 4];
    float4 we1 = *(const float4*)&ew[f4 * 4];
    float4 we2 = *(const float4*)&ew[64 + f4 * 4];
    float nb0 = nb[0];
    const char* mbase = (const char*)mdb + f4 * 8;

    for (int i = wid; i < NN; i += nwv) {
        int vv = bc[i];
        const int* prq = ebuf + (i >> 7) * CAP + (vv >> 16) + q;
        int n = vv & 0xFFFF;
        float a0 = 0.f, a1 = 0.f, a2 = 0.f, a3 = 0.f;
        for (int e = 0; e < n; e += 16) {
            int r0 = prq[e];
            int r1 = prq[e + 4];
            int r2 = prq[e + 8];
            int r3 = prq[e + 12];
            uint2 u0 = *(const uint2*)(mbase + r0);
            uint2 u1 = *(const uint2*)(mbase + r1);
            uint2 u2 = *(const uint2*)(mbase + r2);
            uint2 u3 = *(const uint2*)(mbase + r3);
            ACC4(u0); ACC4(u1); ACC4(u2); ACC4(u3);
        }
        a0 += __shfl_xor(a0, 32, 64); a1 += __shfl_xor(a1, 32, 64);
        a2 += __shfl_xor(a2, 32, 64); a3 += __shfl_xor(a3, 32, 64);
        a0 += __shfl_xor(a0, 16, 64); a1 += __shfl_xor(a1, 16, 64);
        a2 += __shfl_xor(a2, 16, 64); a3 += __shfl_xor(a3, 16, 64);

        float di = dinv[i];
        float v0 = fmaxf(di * a0 + bj.x, 0.f);
        float v1 = fmaxf(di * a1 + bj.y, 0.f);
        float v2 = fmaxf(di * a2 + bj.z, 0.f);
        float v3 = fmaxf(di * a3 + bj.w, 0.f);

        float a  = v0 * wn.x  + v1 * wn.y  + v2 * wn.z  + v3 * wn.w;
        float s1 = v0 * we1.x + v1 * we1.y + v2 * we1.z + v3 * we1.w;
        float s2 = v0 * we2.x + v1 * we2.y + v2 * we2.z + v3 * we2.w;
        #pragma unroll
        for (int off = 8; off; off >>= 1) {
            a  += __shfl_xor(a,  off, 64);
            s1 += __shfl_xor(s1, off, 64);
            s2 += __shfl_xor(s2, off, 64);
        }
        if (lane == 0) {
            out_node[i] = 1.f / (1.f + expf(-(a + nb0)));
            ssrc[i] = s1;
            sdst[i] = s2;
        }
    }
}

// ---------------- edge scores (x4 vectorized) -------------------------------

__global__ __launch_bounds__(256) void k_edge(const int4* __restrict__ row4, const int4* __restrict__ col4,
                                              const float* __restrict__ ssrc, const float* __restrict__ sdst,
                                              const float* __restrict__ eb, float4* __restrict__ out4) {
    constexpr int NQ = EE / 4;
    int i = blockIdx.x * 256 + threadIdx.x;
    if (i >= NQ) return;
    float eb0 = eb[0];
    int4 r = row4[i], c = col4[i];
    float4 o;
    float z;
    z = ssrc[r.x] + sdst[c.x] + eb0; o.x = 1.f / (1.f + expf(-z));
    z = ssrc[r.y] + sdst[c.y] + eb0; o.y = 1.f / (1.f + expf(-z));
    z = ssrc[r.z] + sdst[c.z] + eb0; o.z = 1.f / (1.f + expf(-z));
    z = ssrc[r.w] + sdst[c.w] + eb0; o.w = 1.f / (1.f + expf(-z));
    out4[i] = o;
}

extern "C" void kernel_launch(void* const* d_in, const int* in_sizes, int n_in,
                              void* d_out, int out_size, void* d_ws, size_t ws_size,
                              hipStream_t stream) {
    const float* x    = (const float*)d_in[0];
    const int*   ei   = (const int*)d_in[1];
    const float* fc_w = (const float*)d_in[2];
    const float* fc_b = (const float*)d_in[3];
    const float* c1w  = (const float*)d_in[4];
    const float* c1b  = (const float*)d_in[5];
    const float* c2w  = (const float*)d_in[6];
    const float* c2b  = (const float*)d_in[7];
    const float* nw   = (const float*)d_in[8];
    const float* nb   = (const float*)d_in[9];
    const float* ew   = (const float*)d_in[10];
    const float* eb   = (const float*)d_in[11];
    const int* row = ei;        // edge_index[0]
    const int* col = ei + EE;   // edge_index[1]

    // workspace layout (4B units): ~38.5 MB total
    constexpr int NP    = 100352;
    constexpr int MDSZ  = NN * HID / 2 + 32;   // (NN+1) rows of 64 bf16, in floats
    float* ws   = (float*)d_ws;
    float* dinv = ws;                               // NP
    int*   bc   = (int*)(ws + NP);                  // NP
    int*   gcur = (int*)(ws + 2 * NP);              // 1024
    unsigned short* wct = (unsigned short*)(ws + 2 * NP + 1024);  // 8192 bf16 = 4096 f
    float* bvec = ws + 2 * NP + 1024 + 4096;        // 64 (+pad to 128)
    unsigned short* w2t = (unsigned short*)(bvec + 128);          // 4096 bf16 = 2048 f
    int*   ebuf = (int*)(bvec + 128 + 2048);        // NBUCK*CAP
    float* md1f = (float*)(ebuf + NBUCK * CAP);     // md1 bf16 [(NN+1)*HID]
    float* md2f = md1f + MDSZ;                      // md2 bf16 [(NN+1)*HID]
    unsigned short* md1 = (unsigned short*)md1f;
    unsigned short* md2 = (unsigned short*)md2f;
    int* zrow1 = (int*)((char*)md1 + (size_t)NN * HID * 2);
    int* zrow2 = (int*)((char*)md2 + (size_t)NN * HID * 2);
    float* ssrc = md1f;                             // alias: md1 dead after k_gmm
    float* sdst = md1f + NP;

    float* out_edge = (float*)d_out;
    float* out_node = out_edge + EE;

    const int nbQ = (EE / 4 + 255) / 256;       // 1563 edge-quad blocks
    const int nbM = (NTILE + 3) / 4;            // 1563 MFMA blocks (4 waves = 4 tiles)
    const int nbF = (NN + 63) / 64;             // 1563 fused gather+mm blocks

    // ---- init + bucketize (+ weight prep merged) + padded node sort ----
    k_init    <<<(NBUCK + 255) / 256, 256, 0, stream>>>(gcur, zrow1, zrow2);
    k_bscatter<<<NCB + 13, 1024, 0, stream>>>(row, col, gcur, ebuf,
                                              fc_w, fc_b, c1w, c2w, wct, bvec, w2t);
    k_bsortip <<<NBUCK, 512, 0, stream>>>(gcur, ebuf, bc, dinv);

    // ---- MFMA transform 1, fused gather1+conv2 transform ----
    k_mmx<<<nbM, 256, 0, stream>>>(x, wct, bvec, dinv, md1);
    k_gmm<<<nbF, 256, 0, stream>>>(md1, ebuf, bc, dinv, c1b, w2t, md2);

    // ---- gather 2 fused with scores ----
    k_gather2s<<<2048, 256, 0, stream>>>(md2, ebuf, bc, dinv, c2b,
                                         nw, nb, ew, out_node, ssrc, sdst);

    // ---- edge scores ----
    k_edge<<<nbQ, 256, 0, stream>>>((const int4*)row, (const int4*)col,
                                    ssrc, sdst, eb, (float4*)out_edge);
}